// Round 10
// baseline (8331.495 us; speedup 1.0000x reference)
//
#include <hip/hip_runtime.h>
#include <hip/hip_bf16.h>
#include <math.h>

#define BB 256
#define TT 512
#define INW 128
#define EH 512
#define GH 512

#define NGB 16           // column-slice blocks per group
#define MG 16            // batch rows per group
#define NB 32            // output cols per block
#define HXS (BB*256)     // u64 words per tagged h slot [256 rows][256 col-pairs]

typedef __attribute__((ext_vector_type(8))) short bf16x8;
typedef __attribute__((ext_vector_type(4))) float f32x4;
typedef __attribute__((ext_vector_type(4))) unsigned int u32x4;
typedef unsigned long long ull;

__device__ __forceinline__ float sigm(float x){ return 1.0f/(1.0f+__expf(-x)); }
__device__ __forceinline__ short f2bf(float x){
    __hip_bfloat16 h = __float2bfloat16(x);
    return *reinterpret_cast<short*>(&h);
}

// agent-scope relaxed (IC-coherent) — proven r3/r4 data path
__device__ __forceinline__ ull ld_coh64(const ull* p){
    return __hip_atomic_load(p, __ATOMIC_RELAXED, __HIP_MEMORY_SCOPE_AGENT);
}
__device__ __forceinline__ void st_coh64(ull* p, ull v){
    __hip_atomic_store(p, v, __ATOMIC_RELAXED, __HIP_MEMORY_SCOPE_AGENT);
}

// tagged validate-and-stage: thread owns 8 consecutive u64 (tag|2xbf16 each).
// Masked per-lane reloads (only missing words refetch) + s_sleep backoff.
// Data+tag share one 8B word (single-copy atomic) => no fences, no drains.
__device__ __forceinline__ void vstage8(const ull* gp, unsigned e, char* sbuf,
                                        int row, int kb){
    ull w[8]; unsigned ok = 0; long rounds = 0;
    for(;;){
        #pragma unroll
        for (int k = 0; k < 8; ++k) if (!(ok & (1u<<k))) w[k] = ld_coh64(gp + k);
        #pragma unroll
        for (int k = 0; k < 8; ++k)
            if (!(ok & (1u<<k)) && (unsigned)(w[k] >> 32) == e) ok |= (1u<<k);
        if (ok == 255u) break;
        __builtin_amdgcn_s_sleep(2);
        if (++rounds > (1L << 20)) break;   // escape hatch, never hit legitimately
    }
    const int sw = (row & 7) << 4;
    u32x4 a, b;
    a[0]=(unsigned)w[0]; a[1]=(unsigned)w[1]; a[2]=(unsigned)w[2]; a[3]=(unsigned)w[3];
    b[0]=(unsigned)w[4]; b[1]=(unsigned)w[5]; b[2]=(unsigned)w[6]; b[3]=(unsigned)w[7];
    *(u32x4*)(sbuf + row*1024 + ( kb       ^ sw)) = a;
    *(u32x4*)(sbuf + row*1024 + ((kb + 16) ^ sw)) = b;
}

// publish one bf16 (paired across lanes) as tagged u64; even lane stores
__device__ __forceinline__ void pub_pair(ull* base_pair, unsigned mine, int l15, unsigned e){
    unsigned oth = __shfl_xor(mine, 1);
    if (!(l15 & 1)) st_coh64(base_pair, ((ull)e << 32) | ((ull)oth << 16) | mine);
}

// scalar bf16 write into swizzled LDS h-tile at global col C, row r
__device__ __forceinline__ void lds_h16(char* sbuf, int r, int C, short v){
    int C2 = C * 2;
    *(short*)(sbuf + r*1024 + ((C2 & ~15) ^ ((r & 7) << 4)) + (C2 & 15)) = v;
}

// ================= ENCODER ====================================================================
__global__ __launch_bounds__(512, 1) void enc_kernel(
    const float* __restrict__ src,   // [256][512][128]
    const float* __restrict__ Wi,    // [1536][128] rows r,z,n
    const float* __restrict__ Wh,    // [1536][512]
    ull*         __restrict__ hx,    // [2][256][256] tagged
    float*       __restrict__ hencf) // [256][512] f32 final state (aliases hx slot0)
{
    __shared__ __align__(16) char sH[MG*1024];   // [16][512] bf16, swizzled
    __shared__ __align__(16) char sX[MG*256];    // [16][128] bf16, swizzled
    __shared__ float sR[MG*33], sZ[MG*33], sHfp[MG*33];

    const int bid = blockIdx.x, g = bid >> 4, ng = bid & 15;
    const int tid = threadIdx.x, wid = tid >> 6, lane = tid & 63;
    const int l15 = lane & 15, lk = lane >> 4;
    const int j0 = ng * NB, b0 = g * MG;
    const int gate = wid >> 1, ct = wid & 1, col = ct*16 + l15;

    // persistent weight fragments (r4-verified loader)
    bf16x8 whB[16], wxB[4];
    if (wid < 6){
        const float* wrh = Wh + (size_t)(gate*EH + j0 + col) * EH;
        const float* wrx = Wi + (size_t)(gate*EH + j0 + col) * INW;
        #pragma unroll
        for (int kt = 0; kt < 16; ++kt){
            int ke = kt*32 + lk*8;
            float4 f0 = *(const float4*)(wrh + ke);
            float4 f1 = *(const float4*)(wrh + ke + 4);
            bf16x8 v;
            v[0]=f2bf(f0.x); v[1]=f2bf(f0.y); v[2]=f2bf(f0.z); v[3]=f2bf(f0.w);
            v[4]=f2bf(f1.x); v[5]=f2bf(f1.y); v[6]=f2bf(f1.z); v[7]=f2bf(f1.w);
            whB[kt] = v;
        }
        #pragma unroll
        for (int kt = 0; kt < 4; ++kt){
            int ke = kt*32 + lk*8;
            float4 f0 = *(const float4*)(wrx + ke);
            float4 f1 = *(const float4*)(wrx + ke + 4);
            bf16x8 v;
            v[0]=f2bf(f0.x); v[1]=f2bf(f0.y); v[2]=f2bf(f0.z); v[3]=f2bf(f0.w);
            v[4]=f2bf(f1.x); v[5]=f2bf(f1.y); v[6]=f2bf(f1.z); v[7]=f2bf(f1.w);
            wxB[kt] = v;
        }
    }

    const int vrow = tid >> 5;                 // validate mapping: 8 u64/thread
    const int vp0  = (tid & 31) * 8;
    const int vkb  = (tid & 31) * 32;
    const int vprod= (tid & 31) >> 1;          // producer slice of my chunk
    const int xrow = tid >> 4, xk = (tid & 15) * 8;   // x staging (tid<256)

    // prologue: h(0)=0 directly in LDS; fp32 state 0; x(0) packed
    sHfp[(tid >> 5)*33 + (tid & 31)] = 0.0f;
    { u32x4 z = {0,0,0,0};
      *(u32x4*)(sH + tid*32) = z; *(u32x4*)(sH + tid*32 + 16) = z; }
    if (tid < 256){
        float4 f0 = *(const float4*)(src + ((size_t)(b0 + xrow)*TT + 0)*INW + xk);
        float4 f1 = *(const float4*)(src + ((size_t)(b0 + xrow)*TT + 0)*INW + xk + 4);
        bf16x8 v;
        v[0]=f2bf(f0.x); v[1]=f2bf(f0.y); v[2]=f2bf(f0.z); v[3]=f2bf(f0.w);
        v[4]=f2bf(f1.x); v[5]=f2bf(f1.y); v[6]=f2bf(f1.z); v[7]=f2bf(f1.w);
        *(bf16x8*)(sX + xrow*256 + ((xk*2) ^ ((xrow & 7) << 4))) = v;
    }
    __syncthreads();

    for (int t = 0; t < TT; ++t){
        const bool last = (t == TT-1);
        ull* pubN = hx + (size_t)((t+1) & 1) * HXS;

        // ---- compute (r9-identical) ----
        f32x4 acc0={0.f,0.f,0.f,0.f}, acc1={0.f,0.f,0.f,0.f}, accx={0.f,0.f,0.f,0.f};
        if (wid < 6){
            const int asw = (l15 & 7) << 4;
            const char* hb = sH + l15*1024;
            const char* xb = sX + l15*256;
            #pragma unroll
            for (int kt = 0; kt < 8; ++kt){ int kb = kt*64 + lk*16;
                acc0 = __builtin_amdgcn_mfma_f32_16x16x32_bf16(*(const bf16x8*)(hb+(kb^asw)), whB[kt], acc0, 0,0,0); }
            #pragma unroll
            for (int kt = 8; kt < 16; ++kt){ int kb = kt*64 + lk*16;
                acc1 = __builtin_amdgcn_mfma_f32_16x16x32_bf16(*(const bf16x8*)(hb+(kb^asw)), whB[kt], acc1, 0,0,0); }
            #pragma unroll
            for (int kt = 0; kt < 4; ++kt){ int kb = kt*64 + lk*16;
                accx = __builtin_amdgcn_mfma_f32_16x16x32_bf16(*(const bf16x8*)(xb+(kb^asw)), wxB[kt], accx, 0,0,0); }
        }
        f32x4 acch = acc0 + acc1;
        if (wid < 2){
            #pragma unroll
            for (int v = 0; v < 4; ++v) sR[(lk*4 + v)*33 + col] = sigm(accx[v] + acch[v]);
        } else if (wid < 4){
            #pragma unroll
            for (int v = 0; v < 4; ++v) sZ[(lk*4 + v)*33 + col] = sigm(accx[v] + acch[v]);
        }
        __syncthreads();
        if (wid == 4 || wid == 5){     // n + combine + tagged publish + own-slice LDS write
            #pragma unroll
            for (int v = 0; v < 4; ++v){
                int row = lk*4 + v;
                float r  = sR[row*33 + col];
                float z  = sZ[row*33 + col];
                float n  = tanhf(accx[v] + r * acch[v]);
                float hp = sHfp[row*33 + col];
                float hn = (1.f - z)*n + z*hp;
                sHfp[row*33 + col] = hn;
                unsigned mine = (unsigned short)f2bf(hn);
                if (!last){
                    pub_pair(pubN + (size_t)(b0+row)*256 + ((j0 + ct*16 + l15) >> 1),
                             mine, l15, (unsigned)(t+1));
                    lds_h16(sH, row, j0 + ct*16 + l15, (short)mine);
                } else {
                    hencf[(size_t)(b0+row)*EH + j0 + col] = hn;
                }
            }
        }
        __syncthreads();   // compute done; sH partial overwrite safe; sX free

        if (!last){
            float4 xf0, xf1;
            if (tid < 256){   // issue x(t+1) loads; latency hides under the spin
                xf0 = *(const float4*)(src + ((size_t)(b0 + xrow)*TT + (t+1))*INW + xk);
                xf1 = *(const float4*)(src + ((size_t)(b0 + xrow)*TT + (t+1))*INW + xk + 4);
            }
            if (vprod != ng)
                vstage8(pubN + (size_t)(b0 + vrow)*256 + vp0, (unsigned)(t+1), sH, vrow, vkb);
            if (tid < 256){
                bf16x8 v;
                v[0]=f2bf(xf0.x); v[1]=f2bf(xf0.y); v[2]=f2bf(xf0.z); v[3]=f2bf(xf0.w);
                v[4]=f2bf(xf1.x); v[5]=f2bf(xf1.y); v[6]=f2bf(xf1.z); v[7]=f2bf(xf1.w);
                *(bf16x8*)(sX + xrow*256 + ((xk*2) ^ ((xrow & 7) << 4))) = v;
            }
        }
        __syncthreads();
    }
}

// ================= enc2gen linear + reparameterized IC sample =================================
__global__ __launch_bounds__(256) void ic_kernel(
    const float* __restrict__ henc,    // [256][512]
    const float* __restrict__ W,       // [1024][512]
    const float* __restrict__ eps,     // [256][512]
    float*       __restrict__ out_icp, // [256][1024] (output #2)
    float*       __restrict__ gh0f,    // [256][512] f32 IC
    ull*         __restrict__ gh0x)    // genHx slot0: tagged epoch-0 IC mirror
{
    __shared__ float hb[EH];
    __shared__ float sIC[GH];
    const int b = blockIdx.x, tid = threadIdx.x;
    for (int k = tid; k < EH; k += 256) hb[k] = henc[(size_t)b*EH + k];
    __syncthreads();

    for (int jj = tid; jj < GH; jj += 256){
        const float4* wm = (const float4*)(W + (size_t)jj * EH);
        const float4* wl = (const float4*)(W + (size_t)(GH + jj) * EH);
        float am = 0.f, al = 0.f;
        #pragma unroll 4
        for (int k4 = 0; k4 < EH/4; ++k4){
            float4 h = ((const float4*)hb)[k4];
            float4 a = wm[k4], c = wl[k4];
            am += h.x*a.x + h.y*a.y + h.z*a.z + h.w*a.w;
            al += h.x*c.x + h.y*c.y + h.z*c.z + h.w*c.w;
        }
        out_icp[(size_t)b*2*GH + jj]      = am;
        out_icp[(size_t)b*2*GH + GH + jj] = al;
        float icv = am + __expf(0.5f * al) * eps[(size_t)b*GH + jj];
        gh0f[(size_t)b*GH + jj] = icv;
        sIC[jj] = icv;
    }
    __syncthreads();
    {   // tagged epoch-0 pairs
        int p = tid;
        unsigned mine = (unsigned short)f2bf(sIC[2*p]);
        unsigned oth  = (unsigned short)f2bf(sIC[2*p + 1]);
        st_coh64(gh0x + (size_t)b*256 + p, ((ull)oth << 16) | mine);   // tag 0
    }
}

// ================= GENERATOR ==================================================================
__global__ __launch_bounds__(512, 1) void gen_kernel(
    const float* __restrict__ Wru,   // [1024][512] rows r then u
    const float* __restrict__ Wc,    // [512][512]
    const float* __restrict__ gh0f,  // [256][512] f32 ic
    ull*         __restrict__ hx,    // [2][256][256] tagged (slot0 = ic tag 0)
    ull*         __restrict__ rh,    // [16][16][256] tagged r*h exchange
    float*       __restrict__ out)   // [256][512][512] (output #1)
{
    __shared__ __align__(16) char sH[MG*1024];    // h(t)  [16][512] bf16 swizzled
    __shared__ __align__(16) char sRH[MG*1024];   // rh(t)
    __shared__ float sU[MG*33], sHfp[MG*33];

    const int bid = blockIdx.x, g = bid >> 4, ng = bid & 15;
    const int tid = threadIdx.x, wid = tid >> 6, lane = tid & 63;
    const int l15 = lane & 15, lk = lane >> 4;
    const int j0 = ng * NB, b0 = g * MG;
    const int gate = wid >> 1, ct = wid & 1, col = ct*16 + l15;
    ull* rhg = rh + (size_t)g * (MG*256);

    // persistent weights: waves 0,1 -> r; 2,3 -> u; 4,5 -> c
    bf16x8 wB[16];
    if (wid < 6){
        const float* wr;
        if (gate == 0)      wr = Wru + (size_t)(j0 + col) * GH;
        else if (gate == 1) wr = Wru + (size_t)(GH + j0 + col) * GH;
        else                wr = Wc  + (size_t)(j0 + col) * GH;
        #pragma unroll
        for (int kt = 0; kt < 16; ++kt){
            int ke = kt*32 + lk*8;
            float4 f0 = *(const float4*)(wr + ke);
            float4 f1 = *(const float4*)(wr + ke + 4);
            bf16x8 v;
            v[0]=f2bf(f0.x); v[1]=f2bf(f0.y); v[2]=f2bf(f0.z); v[3]=f2bf(f0.w);
            v[4]=f2bf(f1.x); v[5]=f2bf(f1.y); v[6]=f2bf(f1.z); v[7]=f2bf(f1.w);
            wB[kt] = v;
        }
    }

    const int vrow = tid >> 5;
    const int vp0  = (tid & 31) * 8;
    const int vkb  = (tid & 31) * 32;
    const int vprod= (tid & 31) >> 1;

    // prologue: fp32 state + tagged IC (epoch 0) -> sH (no skip: ic wrote all slices)
    sHfp[(tid >> 5)*33 + (tid & 31)] =
        gh0f[(size_t)(b0 + (tid >> 5))*GH + j0 + (tid & 31)];
    vstage8(hx + (size_t)(b0 + vrow)*256 + vp0, 0u, sH, vrow, vkb);
    __syncthreads();

    for (int t = 0; t < TT; ++t){
        const bool last = (t == TT-1);
        ull* pubN = hx + (size_t)((t+1) & 1) * HXS;
        const unsigned e = (unsigned)(t + 1);

        // ---- ph1: waves 0,1 -> r (tagged rh publish + own-slice LDS); 2,3 -> u ----
        if (wid < 4){
            const int asw = (l15 & 7) << 4;
            const char* hb = sH + l15*1024;
            f32x4 a0={0.f,0.f,0.f,0.f}, a1={0.f,0.f,0.f,0.f};
            #pragma unroll
            for (int kt = 0; kt < 8; ++kt){ int kb = kt*64 + lk*16;
                a0 = __builtin_amdgcn_mfma_f32_16x16x32_bf16(*(const bf16x8*)(hb+(kb^asw)), wB[kt], a0, 0,0,0); }
            #pragma unroll
            for (int kt = 8; kt < 16; ++kt){ int kb = kt*64 + lk*16;
                a1 = __builtin_amdgcn_mfma_f32_16x16x32_bf16(*(const bf16x8*)(hb+(kb^asw)), wB[kt], a1, 0,0,0); }
            f32x4 acc = a0 + a1;
            if (wid < 2){
                #pragma unroll
                for (int v = 0; v < 4; ++v){
                    int row = lk*4 + v;
                    float hp = sHfp[row*33 + col];
                    unsigned mine = (unsigned short)f2bf(sigm(acc[v]) * hp);
                    pub_pair(rhg + (size_t)row*256 + ((j0 + ct*16 + l15) >> 1),
                             mine, l15, e);
                    lds_h16(sRH, row, j0 + ct*16 + l15, (short)mine);
                }
            } else {
                #pragma unroll
                for (int v = 0; v < 4; ++v)
                    sU[(lk*4 + v)*33 + col] = sigm(acc[v] + 1.0f);
            }
        }
        __syncthreads();   // s1: sU ready; sH/sRH race-free

        if (vprod != ng)
            vstage8(rhg + (size_t)vrow*256 + vp0, e, sRH, vrow, vkb);
        __syncthreads();   // s2: sRH complete

        // ---- ph2: waves 4,5 -> candidate + combine + tagged h publish + out ----
        if (wid == 4 || wid == 5){
            const int asw = (l15 & 7) << 4;
            const char* hb = sRH + l15*1024;
            f32x4 a0={0.f,0.f,0.f,0.f}, a1={0.f,0.f,0.f,0.f};
            #pragma unroll
            for (int kt = 0; kt < 8; ++kt){ int kb = kt*64 + lk*16;
                a0 = __builtin_amdgcn_mfma_f32_16x16x32_bf16(*(const bf16x8*)(hb+(kb^asw)), wB[kt], a0, 0,0,0); }
            #pragma unroll
            for (int kt = 8; kt < 16; ++kt){ int kb = kt*64 + lk*16;
                a1 = __builtin_amdgcn_mfma_f32_16x16x32_bf16(*(const bf16x8*)(hb+(kb^asw)), wB[kt], a1, 0,0,0); }
            f32x4 acc = a0 + a1;
            float hv[4];
            #pragma unroll
            for (int v = 0; v < 4; ++v){
                int row = lk*4 + v;
                float cv = tanhf(acc[v]);
                float u  = sU[row*33 + col];
                float hp = sHfp[row*33 + col];
                float hn = u*hp + (1.f - u)*cv;
                sHfp[row*33 + col] = hn;
                hv[v] = hn;
                unsigned mine = (unsigned short)f2bf(hn);
                if (!last){
                    pub_pair(pubN + (size_t)(b0+row)*256 + ((j0 + ct*16 + l15) >> 1),
                             mine, l15, e);
                    lds_h16(sH, row, j0 + ct*16 + l15, (short)mine);
                }
            }
            #pragma unroll
            for (int v = 0; v < 4; ++v){
                int row = lk*4 + v;
                out[((size_t)(b0+row)*TT + t)*GH + j0 + col] = fminf(fmaxf(hv[v], -5.f), 5.f);
            }
        }
        // waves not in ph2 start validating h(t+1) immediately (disjoint LDS regions)
        if (!last && vprod != ng)
            vstage8(pubN + (size_t)(b0 + vrow)*256 + vp0, e, sH, vrow, vkb);
        __syncthreads();   // s3: sH complete for next step
    }
}

extern "C" void kernel_launch(void* const* d_in, const int* in_sizes, int n_in,
                              void* d_out, int out_size, void* d_ws, size_t ws_size,
                              hipStream_t stream) {
    (void)in_sizes; (void)n_in; (void)out_size; (void)ws_size;

    const float* src    = (const float*)d_in[0];
    const float* eps    = (const float*)d_in[1];
    const float* enc_Wi = (const float*)d_in[2];
    const float* enc_Wh = (const float*)d_in[3];
    const float* e2g    = (const float*)d_in[4];
    const float* gWru   = (const float*)d_in[5];
    const float* gWc    = (const float*)d_in[6];
    float* out = (float*)d_out;

    // workspace 2.5 MB, lifetime-based aliasing:
    //  [0,1MB)      encHx tagged [2][256][256]; slot0 doubles as hencf (written only at
    //               t=511 after all slot0 reads), slot1 doubles as gh0f (written by ic
    //               after enc completes)
    //  [1MB,2MB)    genHx tagged [2][256][256]; slot0 = ic epoch-0 mirror
    //  [2MB,2.5MB)  rh tagged [16][16][256]
    char* ws = (char*)d_ws;
    ull*   encHx = (ull*)(ws);
    ull*   genHx = (ull*)(ws + (1u<<20));
    ull*   rhbuf = (ull*)(ws + (2u<<20));
    float* hencf = (float*)(ws);                   // aliases encHx slot0
    float* gh0f  = (float*)(ws + (512u<<10));      // aliases encHx slot1

    // zero all tagged buffers every launch: kills first-call garbage tags and
    // resets replay residue (captured in the graph, ~2 µs)
    hipMemsetAsync(ws, 0, (size_t)5 << 19, stream);

    enc_kernel<<<dim3(256), dim3(512), 0, stream>>>(src, enc_Wi, enc_Wh, encHx, hencf);
    ic_kernel <<<dim3(256), dim3(256), 0, stream>>>(hencf, e2g, eps,
                                                    out + (size_t)BB*TT*GH, gh0f, genHx);
    gen_kernel<<<dim3(256), dim3(512), 0, stream>>>(gWru, gWc, gh0f, genHx, rhbuf, out);
}